// Round 6
// baseline (179.521 us; speedup 1.0000x reference)
//
#include <hip/hip_runtime.h>
#include <hip/hip_bf16.h>

#if !__has_builtin(__builtin_amdgcn_cvt_pk_f32_fp8) || !__has_builtin(__builtin_amdgcn_cvt_pk_fp8_f32)
#include <hip/hip_fp8.h>
#endif

#define Bx 512
#define Lx 256
#define Dx 100
#define Kx 14
#define VROWS 50001        // vocab + padding row
#define NEG_ROWS 1280      // 20 * 64
#define NEG_CHUNKS 5
#define NEG_CHUNK 256      // rows per neg block
#define NBLK_ATTN Bx
#define NBLK_NEG (Bx * NEG_CHUNKS)
#define ACC_N (4 + Bx * Dx)   // acc[0..3] + g[Bx*Dx]

#define PAD8  128          // bytes per fp8 row (128 B, exactly 1 cache line)
#define RAW8  100          // compact fallback

typedef float floatx2 __attribute__((ext_vector_type(2)));

__device__ __forceinline__ float dot4(float4 a, float4 b) {
    return a.x * b.x + a.y * b.y + a.z * b.z + a.w * b.w;
}

__device__ __forceinline__ float4 fp8x4_dec(unsigned u) {
#if __has_builtin(__builtin_amdgcn_cvt_pk_f32_fp8)
    floatx2 lo = __builtin_amdgcn_cvt_pk_f32_fp8((int)u, false);
    floatx2 hi = __builtin_amdgcn_cvt_pk_f32_fp8((int)u, true);
    return make_float4(lo.x, lo.y, hi.x, hi.y);
#else
    __hip_fp8_e4m3 a, b, c, d;
    a.__x = (unsigned char)(u & 0xFF);
    b.__x = (unsigned char)((u >> 8) & 0xFF);
    c.__x = (unsigned char)((u >> 16) & 0xFF);
    d.__x = (unsigned char)((u >> 24) & 0xFF);
    return make_float4((float)a, (float)b, (float)c, (float)d);
#endif
}

__device__ __forceinline__ unsigned fp8x4_enc(float4 v) {
#if __has_builtin(__builtin_amdgcn_cvt_pk_fp8_f32)
    int p = 0;
    p = __builtin_amdgcn_cvt_pk_fp8_f32(v.x, v.y, p, false);
    p = __builtin_amdgcn_cvt_pk_fp8_f32(v.z, v.w, p, true);
    return (unsigned)p;
#else
    __hip_fp8_e4m3 a(v.x), b(v.y), c(v.z), d(v.w);
    return (unsigned)a.__x | ((unsigned)b.__x << 8) |
           ((unsigned)c.__x << 16) | ((unsigned)d.__x << 24);
#endif
}

// ---- convert fp32 table -> fp8 rows (stride RS8 bytes); zero acc+g ----
__global__ __launch_bounds__(256) void convert_kernel(
    const float* __restrict__ table, unsigned char* __restrict__ tb8,
    float* __restrict__ acc, int RS8, int padded)
{
    const int gid = blockIdx.x * 256 + threadIdx.x;
    if (gid < ACC_N) acc[gid] = 0.0f;
    const int row = gid >> 5;          // 32 dword slots per row
    const int c   = gid & 31;
    if (row >= VROWS) return;
    if (c < 25) {
        const float4 v = *reinterpret_cast<const float4*>(
            table + (size_t)row * Dx + c * 4);
        *reinterpret_cast<unsigned*>(tb8 + (size_t)row * RS8 + c * 4) = fp8x4_enc(v);
    } else if (padded) {
        *reinterpret_cast<unsigned*>(tb8 + (size_t)row * RS8 + c * 4) = 0u;
    }
}

// ---- fused: attn blocks (bid < Bx) + neg-gather blocks ----
__global__ __launch_bounds__(256) void fused_gather(
    const int* __restrict__ pos_ids, const int* __restrict__ neg_ids,
    const unsigned char* __restrict__ tb8,
    const float* __restrict__ W_att, const float* __restrict__ Wk,
    const float* __restrict__ bk, const float* __restrict__ Wf,
    const float* __restrict__ bf, float* __restrict__ pt_out,
    float* __restrict__ rs_out, float* __restrict__ acc, float* __restrict__ g,
    int RS8)
{
    const int tid  = threadIdx.x;
    const int grp  = tid >> 5;      // 0..7
    const int lane = tid & 31;      // 0..31
    const int bid  = blockIdx.x;

    __shared__ __align__(16) float4 part4[8][26];
    __shared__ int   ids[Lx];
    __shared__ float red[Lx];
    __shared__ __align__(16) float ys_sh[104];
    __shared__ __align__(16) float t_sh[104];
    __shared__ float zs_sh[104];
    __shared__ float pt_sh[Kx];
    __shared__ float m_sh[8], s_sh[8], sc_sh[8];

    float* pf = (float*)part4;      // [8][104] float view

    if (bid >= NBLK_ATTN) {
        // ============ NEG-GATHER BLOCK (fp8, 1 line/row, nt, ILP 8) ============
        const int j = bid - NBLK_ATTN;              // 0..2559
        const int b = j / NEG_CHUNKS;
        const int c = j - b * NEG_CHUNKS;
        const int* idp = neg_ids + (size_t)b * NEG_ROWS + c * NEG_CHUNK;

        ids[tid] = idp[tid];
        __syncthreads();

        if (lane < 25) {
            const int o = lane * 4;
            float4 a[8];
            #pragma unroll
            for (int t = 0; t < 8; ++t) a[t] = make_float4(0.f, 0.f, 0.f, 0.f);
            for (int r = grp; r < NEG_CHUNK; r += 64) {
                unsigned u[8];
                #pragma unroll
                for (int t = 0; t < 8; ++t)
                    u[t] = __builtin_nontemporal_load(
                        (const unsigned*)(tb8 + (size_t)ids[r + 8 * t] * RS8 + o));
                #pragma unroll
                for (int t = 0; t < 8; ++t) {
                    const float4 v = fp8x4_dec(u[t]);
                    a[t].x += v.x; a[t].y += v.y; a[t].z += v.z; a[t].w += v.w;
                }
            }
            #pragma unroll
            for (int t = 1; t < 8; ++t) {
                a[0].x += a[t].x; a[0].y += a[t].y;
                a[0].z += a[t].z; a[0].w += a[t].w;
            }
            part4[grp][lane] = a[0];
        }
        __syncthreads();
        if (tid < Dx) {
            float s = 0.f;
            #pragma unroll
            for (int gg = 0; gg < 8; ++gg) s += pf[gg * 104 + tid];
            atomicAdd(&g[(size_t)b * Dx + tid], s);
        }
        return;
    }

    // ================= ATTN BLOCK =================
    // Gather each pos row ONCE into registers (lane<25 holds 32 packed uints),
    // decode twice: pass A (ys) and pass B (online softmax + zs).
    const int b = bid;
    ids[tid] = pos_ids[(size_t)b * Lx + tid];
    __syncthreads();

    unsigned ereg[32];
    #pragma unroll
    for (int k = 0; k < 32; ++k) ereg[k] = 0u;
    if (lane < 25) {
        const int o = lane * 4;
        #pragma unroll
        for (int k = 0; k < 32; ++k)
            ereg[k] = __builtin_nontemporal_load(
                (const unsigned*)(tb8 + (size_t)ids[grp + 8 * k] * RS8 + o));
    }

    // ---- pass A: ys = mean_l e ----
    {
        float4 a0 = {0.f, 0.f, 0.f, 0.f};
        #pragma unroll
        for (int k = 0; k < 32; ++k) {
            const float4 v = fp8x4_dec(ereg[k]);
            a0.x += v.x; a0.y += v.y; a0.z += v.z; a0.w += v.w;
        }
        if (lane < 25) part4[grp][lane] = a0;
    }
    __syncthreads();
    if (tid < Dx) {
        float s = 0.f;
        #pragma unroll
        for (int gg = 0; gg < 8; ++gg) s += pf[gg * 104 + tid];
        ys_sh[tid] = s * (1.0f / Lx);
    }
    __syncthreads();

    // ---- t = W_att @ ys ----
    if (tid < Dx) {
        const float* wrow = W_att + (size_t)tid * Dx;
        float s = 0.f;
        #pragma unroll 4
        for (int e = 0; e < Dx; ++e) s += wrow[e] * ys_sh[e];
        t_sh[tid] = s;
    }
    if (tid >= Dx && tid < 104) t_sh[tid] = 0.f;
    __syncthreads();

    // ---- pass B: online softmax (f + zs) from registers ----
    {
        const float4 tl = (lane < 25) ? ((const float4*)t_sh)[lane]
                                      : make_float4(0.f, 0.f, 0.f, 0.f);
        float m = -1e30f, ssum = 0.f;
        float4 za = {0.f, 0.f, 0.f, 0.f};
        #pragma unroll
        for (int k = 0; k < 32; ++k) {
            const int id = ids[grp + 8 * k];
            const float4 e = fp8x4_dec(ereg[k]);
            float d = dot4(e, tl);
            #pragma unroll
            for (int o2 = 16; o2 > 0; o2 >>= 1) d += __shfl_xor(d, o2, 32);
            const float fv = (id != 0) ? d : -1e30f;
            const float mn = fmaxf(m, fv);
            const float sc = expf(m - mn);
            const float w  = (id != 0) ? expf(d - mn) : 0.f;
            ssum = ssum * sc + w;
            za.x = za.x * sc + w * e.x;
            za.y = za.y * sc + w * e.y;
            za.z = za.z * sc + w * e.z;
            za.w = za.w * sc + w * e.w;
            m = mn;
        }
        if (lane == 0) { m_sh[grp] = m; s_sh[grp] = ssum; }
        if (lane < 25) part4[grp][lane] = za;
    }
    __syncthreads();
    if (tid < 8) {
        float M = -1e30f;
        #pragma unroll
        for (int gg = 0; gg < 8; ++gg) M = fmaxf(M, m_sh[gg]);
        sc_sh[tid] = expf(m_sh[tid] - M);
    }
    __syncthreads();
    if (tid < Dx) {
        float S = 0.f, z = 0.f;
        #pragma unroll
        for (int gg = 0; gg < 8; ++gg) {
            S += s_sh[gg] * sc_sh[gg];
            z += pf[gg * 104 + tid] * sc_sh[gg];
        }
        zs_sh[tid] = z / S;
    }
    __syncthreads();

    // ---- pt = sigmoid(zs @ Wk + bk) ----
    if (tid < Kx) {
        float s = bk[tid];
        for (int d = 0; d < Dx; ++d) s += zs_sh[d] * Wk[d * Kx + tid];
        const float pk = 1.0f / (1.0f + expf(-s));
        pt_sh[tid] = pk;
        pt_out[(size_t)b * Kx + tid] = pk;
    }
    __syncthreads();

    // ---- rs = bf + pt @ Wf ; pos partial = rs . zs ----
    float contrib = 0.f;
    if (tid < Dx) {
        float r = bf[tid];
        #pragma unroll
        for (int k = 0; k < Kx; ++k) r += pt_sh[k] * Wf[k * Dx + tid];
        rs_out[(size_t)b * Dx + tid] = r;
        contrib = r * zs_sh[tid];
    }
    red[tid] = contrib;
    __syncthreads();
    for (int s = 128; s > 0; s >>= 1) {
        if (tid < s) red[tid] += red[tid + s];
        __syncthreads();
    }
    if (tid == 0) atomicAdd(&acc[0], red[0]);
}

// ---- loss: neg dot + reg term + final (single block) ----
__global__ __launch_bounds__(1024) void loss_kernel(
    const float* __restrict__ Wf, const float* __restrict__ acc,
    const float* __restrict__ g, const float* __restrict__ rs,
    float* __restrict__ out)
{
    __shared__ float n[Kx];
    __shared__ float red[1024];
    const int tid = threadIdx.x;

    float v = 0.f;
    for (int i = tid; i < Bx * Dx; i += 1024) v += g[i] * rs[i];
    red[tid] = v;
    __syncthreads();
    for (int s = 512; s > 0; s >>= 1) {
        if (tid < s) red[tid] += red[tid + s];
        __syncthreads();
    }
    const float neg_term = red[0] * (1.0f / 64.0f);
    __syncthreads();

    if (tid < Kx) {
        float s = 0.f;
        for (int d = 0; d < Dx; ++d) {
            const float w = Wf[tid * Dx + d];
            s += w * w;
        }
        n[tid] = sqrtf(s);
    }
    __syncthreads();

    float vv = 0.f;
    if (tid < Kx * Kx) {
        const int i = tid / Kx;
        const int j = tid - i * Kx;
        const float x = n[i] * n[j] - 1.0f;
        vv = x * x;
    }
    red[tid] = vv;
    __syncthreads();
    for (int s = 512; s > 0; s >>= 1) {
        if (tid < s) red[tid] += red[tid + s];
        __syncthreads();
    }
    if (tid == 0) {
        const float reg = sqrtf(red[0]);
        const float margin = 1.0f - neg_term + acc[0];
        out[0] = fmaxf(margin, 0.0f) + reg;   // LAMBDA = 1.0
    }
}

extern "C" void kernel_launch(void* const* d_in, const int* in_sizes, int n_in,
                              void* d_out, int out_size, void* d_ws, size_t ws_size,
                              hipStream_t stream) {
    const int*   pos_ids = (const int*)  d_in[0];
    const int*   neg_ids = (const int*)  d_in[1];
    const float* table   = (const float*)d_in[2];
    const float* W_att   = (const float*)d_in[3];
    const float* Wk      = (const float*)d_in[4];
    const float* bk      = (const float*)d_in[5];
    const float* Wf      = (const float*)d_in[6];
    const float* bf      = (const float*)d_in[7];

    float* out    = (float*)d_out;
    float* pt_out = out + 1;
    float* rs_out = out + 1 + (size_t)Bx * Kx;

    const size_t need_pad = (size_t)VROWS * PAD8 + 16 + (size_t)ACC_N * 4;
    const int padded = (ws_size >= need_pad) ? 1 : 0;
    const int RS8 = padded ? PAD8 : RAW8;

    unsigned char* tb8 = (unsigned char*)d_ws;
    size_t acc_off = (size_t)VROWS * RS8;
    acc_off = (acc_off + 15) & ~(size_t)15;
    float* acc = (float*)((char*)d_ws + acc_off);
    float* g   = acc + 4;

    const int nthreads = VROWS * 32;
    convert_kernel<<<(nthreads + 255) / 256, 256, 0, stream>>>(
        table, tb8, acc, RS8, padded);
    fused_gather<<<NBLK_ATTN + NBLK_NEG, 256, 0, stream>>>(
        pos_ids, neg_ids, tb8, W_att, Wk, bk, Wf, bf,
        pt_out, rs_out, acc, g, RS8);
    loss_kernel<<<1, 1024, 0, stream>>>(Wf, acc, g, rs_out, out);
}

// Round 7
// 137.998 us; speedup vs baseline: 1.3009x; 1.3009x over previous
//
#include <hip/hip_runtime.h>
#include <hip/hip_bf16.h>

#if !__has_builtin(__builtin_amdgcn_cvt_pk_f32_fp8) || !__has_builtin(__builtin_amdgcn_cvt_pk_fp8_f32)
#include <hip/hip_fp8.h>
#endif

#define Bx 512
#define Lx 256
#define Dx 100
#define Kx 14
#define VROWS 50001        // vocab + padding row
#define NEG_ROWS 1280      // 20 * 64
#define NEG_CHUNKS 5
#define NEG_CHUNK 256      // rows per neg block
#define NBLK_ATTN Bx
#define NBLK_NEG (Bx * NEG_CHUNKS)
#define ACC_N (4 + Bx * Dx)   // acc[0..3] + g[Bx*Dx]

#define PAD8  128          // bytes per fp8 row (128 B, exactly 1 cache line)
#define RAW8  100          // compact fallback

typedef float floatx2 __attribute__((ext_vector_type(2)));

__device__ __forceinline__ float dot4(float4 a, float4 b) {
    return a.x * b.x + a.y * b.y + a.z * b.z + a.w * b.w;
}

__device__ __forceinline__ float4 fp8x4_dec(unsigned u) {
#if __has_builtin(__builtin_amdgcn_cvt_pk_f32_fp8)
    floatx2 lo = __builtin_amdgcn_cvt_pk_f32_fp8((int)u, false);
    floatx2 hi = __builtin_amdgcn_cvt_pk_f32_fp8((int)u, true);
    return make_float4(lo.x, lo.y, hi.x, hi.y);
#else
    __hip_fp8_e4m3 a, b, c, d;
    a.__x = (unsigned char)(u & 0xFF);
    b.__x = (unsigned char)((u >> 8) & 0xFF);
    c.__x = (unsigned char)((u >> 16) & 0xFF);
    d.__x = (unsigned char)((u >> 24) & 0xFF);
    return make_float4((float)a, (float)b, (float)c, (float)d);
#endif
}

__device__ __forceinline__ unsigned fp8x4_enc(float4 v) {
#if __has_builtin(__builtin_amdgcn_cvt_pk_fp8_f32)
    int p = 0;
    p = __builtin_amdgcn_cvt_pk_fp8_f32(v.x, v.y, p, false);
    p = __builtin_amdgcn_cvt_pk_fp8_f32(v.z, v.w, p, true);
    return (unsigned)p;
#else
    __hip_fp8_e4m3 a(v.x), b(v.y), c(v.z), d(v.w);
    return (unsigned)a.__x | ((unsigned)b.__x << 8) |
           ((unsigned)c.__x << 16) | ((unsigned)d.__x << 24);
#endif
}

// ---- convert fp32 table -> fp8 rows (stride RS8 bytes); zero acc+g ----
__global__ __launch_bounds__(256) void convert_kernel(
    const float* __restrict__ table, unsigned char* __restrict__ tb8,
    float* __restrict__ acc, int RS8, int padded)
{
    const int gid = blockIdx.x * 256 + threadIdx.x;
    if (gid < ACC_N) acc[gid] = 0.0f;
    const int row = gid >> 5;          // 32 dword slots per row
    const int c   = gid & 31;
    if (row >= VROWS) return;
    if (c < 25) {
        const float4 v = *reinterpret_cast<const float4*>(
            table + (size_t)row * Dx + c * 4);
        *reinterpret_cast<unsigned*>(tb8 + (size_t)row * RS8 + c * 4) = fp8x4_enc(v);
    } else if (padded) {
        *reinterpret_cast<unsigned*>(tb8 + (size_t)row * RS8 + c * 4) = 0u;
    }
}

// ---- fused: attn blocks (bid < Bx) + neg-gather blocks ----
__global__ __launch_bounds__(256) void fused_gather(
    const int* __restrict__ pos_ids, const int* __restrict__ neg_ids,
    const unsigned char* __restrict__ tb8,
    const float* __restrict__ W_att, const float* __restrict__ Wk,
    const float* __restrict__ bk, const float* __restrict__ Wf,
    const float* __restrict__ bf, float* __restrict__ pt_out,
    float* __restrict__ rs_out, float* __restrict__ acc, float* __restrict__ g,
    int RS8)
{
    const int tid  = threadIdx.x;
    const int grp  = tid >> 5;      // 0..7
    const int lane = tid & 31;      // 0..31
    const int bid  = blockIdx.x;

    __shared__ __align__(16) float4 part4[8][26];
    __shared__ int   ids[Lx];
    __shared__ float red[Lx];
    __shared__ __align__(16) float ys_sh[104];
    __shared__ __align__(16) float t_sh[104];
    __shared__ float zs_sh[104];
    __shared__ float pt_sh[Kx];
    __shared__ float m_sh[8], s_sh[8], sc_sh[8];

    float* pf = (float*)part4;      // [8][104] float view

    if (bid >= NBLK_ATTN) {
        // ============ NEG-GATHER BLOCK (fp8, 1 line/row, ILP 4) ============
        const int j = bid - NBLK_ATTN;              // 0..2559
        const int b = j / NEG_CHUNKS;
        const int c = j - b * NEG_CHUNKS;
        const int* idp = neg_ids + (size_t)b * NEG_ROWS + c * NEG_CHUNK;

        ids[tid] = idp[tid];
        __syncthreads();

        if (lane < 25) {
            const int o = lane * 4;
            float4 a0 = {0,0,0,0}, a1 = {0,0,0,0}, a2 = {0,0,0,0}, a3 = {0,0,0,0};
            for (int r = grp; r < NEG_CHUNK; r += 32) {
                const unsigned u0 = *(const unsigned*)(tb8 + (size_t)ids[r]      * RS8 + o);
                const unsigned u1 = *(const unsigned*)(tb8 + (size_t)ids[r + 8]  * RS8 + o);
                const unsigned u2 = *(const unsigned*)(tb8 + (size_t)ids[r + 16] * RS8 + o);
                const unsigned u3 = *(const unsigned*)(tb8 + (size_t)ids[r + 24] * RS8 + o);
                const float4 v0 = fp8x4_dec(u0);
                const float4 v1 = fp8x4_dec(u1);
                const float4 v2 = fp8x4_dec(u2);
                const float4 v3 = fp8x4_dec(u3);
                a0.x += v0.x; a0.y += v0.y; a0.z += v0.z; a0.w += v0.w;
                a1.x += v1.x; a1.y += v1.y; a1.z += v1.z; a1.w += v1.w;
                a2.x += v2.x; a2.y += v2.y; a2.z += v2.z; a2.w += v2.w;
                a3.x += v3.x; a3.y += v3.y; a3.z += v3.z; a3.w += v3.w;
            }
            a0.x += a1.x + a2.x + a3.x; a0.y += a1.y + a2.y + a3.y;
            a0.z += a1.z + a2.z + a3.z; a0.w += a1.w + a2.w + a3.w;
            part4[grp][lane] = a0;
        }
        __syncthreads();
        if (tid < Dx) {
            float s = 0.f;
            #pragma unroll
            for (int gg = 0; gg < 8; ++gg) s += pf[gg * 104 + tid];
            atomicAdd(&g[(size_t)b * Dx + tid], s);
        }
        return;
    }

    // ================= ATTN BLOCK =================
    const int b = bid;
    ids[tid] = pos_ids[(size_t)b * Lx + tid];
    __syncthreads();

    // ---- pass A: ys = mean_l e  (fp8, 1 line/row) ----
    if (lane < 25) {
        const int o = lane * 4;
        float4 a0 = {0,0,0,0}, a1 = {0,0,0,0}, a2 = {0,0,0,0}, a3 = {0,0,0,0};
        for (int r = grp; r < Lx; r += 32) {
            const float4 v0 = fp8x4_dec(*(const unsigned*)(tb8 + (size_t)ids[r]      * RS8 + o));
            const float4 v1 = fp8x4_dec(*(const unsigned*)(tb8 + (size_t)ids[r + 8]  * RS8 + o));
            const float4 v2 = fp8x4_dec(*(const unsigned*)(tb8 + (size_t)ids[r + 16] * RS8 + o));
            const float4 v3 = fp8x4_dec(*(const unsigned*)(tb8 + (size_t)ids[r + 24] * RS8 + o));
            a0.x += v0.x; a0.y += v0.y; a0.z += v0.z; a0.w += v0.w;
            a1.x += v1.x; a1.y += v1.y; a1.z += v1.z; a1.w += v1.w;
            a2.x += v2.x; a2.y += v2.y; a2.z += v2.z; a2.w += v2.w;
            a3.x += v3.x; a3.y += v3.y; a3.z += v3.z; a3.w += v3.w;
        }
        a0.x += a1.x + a2.x + a3.x; a0.y += a1.y + a2.y + a3.y;
        a0.z += a1.z + a2.z + a3.z; a0.w += a1.w + a2.w + a3.w;
        part4[grp][lane] = a0;
    }
    __syncthreads();
    if (tid < Dx) {
        float s = 0.f;
        #pragma unroll
        for (int gg = 0; gg < 8; ++gg) s += pf[gg * 104 + tid];
        ys_sh[tid] = s * (1.0f / Lx);
    }
    __syncthreads();

    // ---- t = W_att @ ys ----
    if (tid < Dx) {
        const float* wrow = W_att + (size_t)tid * Dx;
        float s = 0.f;
        #pragma unroll 4
        for (int e = 0; e < Dx; ++e) s += wrow[e] * ys_sh[e];
        t_sh[tid] = s;
    }
    if (tid >= Dx && tid < 104) t_sh[tid] = 0.f;
    __syncthreads();

    // ---- pass B: online softmax, f + zs in one gather (fp8, L2-warm) ----
    {
        const float4 tl = (lane < 25) ? ((const float4*)t_sh)[lane]
                                      : make_float4(0.f, 0.f, 0.f, 0.f);
        float m = -1e30f, ssum = 0.f;
        float4 za = {0.f, 0.f, 0.f, 0.f};
        for (int r = grp; r < Lx; r += 16) {
            const int id0 = ids[r];
            const int id1 = ids[r + 8];
            float4 e0 = {0,0,0,0}, e1 = {0,0,0,0};
            if (lane < 25) {
                e0 = fp8x4_dec(*(const unsigned*)(tb8 + (size_t)id0 * RS8 + lane * 4));
                e1 = fp8x4_dec(*(const unsigned*)(tb8 + (size_t)id1 * RS8 + lane * 4));
            }
            float d0 = dot4(e0, tl);
            float d1 = dot4(e1, tl);
            #pragma unroll
            for (int o = 16; o > 0; o >>= 1) {
                d0 += __shfl_xor(d0, o, 32);
                d1 += __shfl_xor(d1, o, 32);
            }
            const float f0 = (id0 != 0) ? d0 : -1e30f;
            const float f1 = (id1 != 0) ? d1 : -1e30f;
            const float mn = fmaxf(m, fmaxf(f0, f1));
            const float sc = expf(m - mn);
            const float w0 = (id0 != 0) ? expf(d0 - mn) : 0.f;
            const float w1 = (id1 != 0) ? expf(d1 - mn) : 0.f;
            ssum = ssum * sc + w0 + w1;
            za.x = za.x * sc + w0 * e0.x + w1 * e1.x;
            za.y = za.y * sc + w0 * e0.y + w1 * e1.y;
            za.z = za.z * sc + w0 * e0.z + w1 * e1.z;
            za.w = za.w * sc + w0 * e0.w + w1 * e1.w;
            m = mn;
        }
        if (lane == 0) { m_sh[grp] = m; s_sh[grp] = ssum; }
        if (lane < 25) part4[grp][lane] = za;
    }
    __syncthreads();
    if (tid < 8) {
        float M = -1e30f;
        #pragma unroll
        for (int gg = 0; gg < 8; ++gg) M = fmaxf(M, m_sh[gg]);
        sc_sh[tid] = expf(m_sh[tid] - M);
    }
    __syncthreads();
    if (tid < Dx) {
        float S = 0.f, z = 0.f;
        #pragma unroll
        for (int gg = 0; gg < 8; ++gg) {
            S += s_sh[gg] * sc_sh[gg];
            z += pf[gg * 104 + tid] * sc_sh[gg];
        }
        zs_sh[tid] = z / S;
    }
    __syncthreads();

    // ---- pt = sigmoid(zs @ Wk + bk) ----
    if (tid < Kx) {
        float s = bk[tid];
        for (int d = 0; d < Dx; ++d) s += zs_sh[d] * Wk[d * Kx + tid];
        const float pk = 1.0f / (1.0f + expf(-s));
        pt_sh[tid] = pk;
        pt_out[(size_t)b * Kx + tid] = pk;
    }
    __syncthreads();

    // ---- rs = bf + pt @ Wf ; pos partial = rs . zs ----
    float contrib = 0.f;
    if (tid < Dx) {
        float r = bf[tid];
        #pragma unroll
        for (int k = 0; k < Kx; ++k) r += pt_sh[k] * Wf[k * Dx + tid];
        rs_out[(size_t)b * Dx + tid] = r;
        contrib = r * zs_sh[tid];
    }
    red[tid] = contrib;
    __syncthreads();
    for (int s = 128; s > 0; s >>= 1) {
        if (tid < s) red[tid] += red[tid + s];
        __syncthreads();
    }
    if (tid == 0) atomicAdd(&acc[0], red[0]);
}

// ---- loss: neg dot + reg term + final (single block) ----
__global__ __launch_bounds__(1024) void loss_kernel(
    const float* __restrict__ Wf, const float* __restrict__ acc,
    const float* __restrict__ g, const float* __restrict__ rs,
    float* __restrict__ out)
{
    __shared__ float n[Kx];
    __shared__ float red[1024];
    const int tid = threadIdx.x;

    float v = 0.f;
    for (int i = tid; i < Bx * Dx; i += 1024) v += g[i] * rs[i];
    red[tid] = v;
    __syncthreads();
    for (int s = 512; s > 0; s >>= 1) {
        if (tid < s) red[tid] += red[tid + s];
        __syncthreads();
    }
    const float neg_term = red[0] * (1.0f / 64.0f);
    __syncthreads();

    if (tid < Kx) {
        float s = 0.f;
        for (int d = 0; d < Dx; ++d) {
            const float w = Wf[tid * Dx + d];
            s += w * w;
        }
        n[tid] = sqrtf(s);
    }
    __syncthreads();

    float vv = 0.f;
    if (tid < Kx * Kx) {
        const int i = tid / Kx;
        const int j = tid - i * Kx;
        const float x = n[i] * n[j] - 1.0f;
        vv = x * x;
    }
    red[tid] = vv;
    __syncthreads();
    for (int s = 512; s > 0; s >>= 1) {
        if (tid < s) red[tid] += red[tid + s];
        __syncthreads();
    }
    if (tid == 0) {
        const float reg = sqrtf(red[0]);
        const float margin = 1.0f - neg_term + acc[0];
        out[0] = fmaxf(margin, 0.0f) + reg;   // LAMBDA = 1.0
    }
}

extern "C" void kernel_launch(void* const* d_in, const int* in_sizes, int n_in,
                              void* d_out, int out_size, void* d_ws, size_t ws_size,
                              hipStream_t stream) {
    const int*   pos_ids = (const int*)  d_in[0];
    const int*   neg_ids = (const int*)  d_in[1];
    const float* table   = (const float*)d_in[2];
    const float* W_att   = (const float*)d_in[3];
    const float* Wk      = (const float*)d_in[4];
    const float* bk      = (const float*)d_in[5];
    const float* Wf      = (const float*)d_in[6];
    const float* bf      = (const float*)d_in[7];

    float* out    = (float*)d_out;
    float* pt_out = out + 1;
    float* rs_out = out + 1 + (size_t)Bx * Kx;

    const size_t need_pad = (size_t)VROWS * PAD8 + 16 + (size_t)ACC_N * 4;
    const int padded = (ws_size >= need_pad) ? 1 : 0;
    const int RS8 = padded ? PAD8 : RAW8;

    unsigned char* tb8 = (unsigned char*)d_ws;
    size_t acc_off = (size_t)VROWS * RS8;
    acc_off = (acc_off + 15) & ~(size_t)15;
    float* acc = (float*)((char*)d_ws + acc_off);
    float* g   = acc + 4;

    const int nthreads = VROWS * 32;
    convert_kernel<<<(nthreads + 255) / 256, 256, 0, stream>>>(
        table, tb8, acc, RS8, padded);
    fused_gather<<<NBLK_ATTN + NBLK_NEG, 256, 0, stream>>>(
        pos_ids, neg_ids, tb8, W_att, Wk, bk, Wf, bf,
        pt_out, rs_out, acc, g, RS8);
    loss_kernel<<<1, 1024, 0, stream>>>(Wf, acc, g, rs_out, out);
}